// Round 1
// baseline (1017.695 us; speedup 1.0000x reference)
//
#include <hip/hip_runtime.h>

// Causal conv1d: out[b,h,t] = sum_{c,k} x[b,c,t+k-3] * W[h, c*4+k] + bias[h]
// B=8, C=256, T=4096, H=512, K=4  (fixed by setup_inputs)

#define Bb 8
#define Cc 256
#define Tt 4096
#define Hh 512
#define Kk 4

#define TT 256   // t-tile per block (== blockDim.x)
#define HT 8     // h outputs per thread
#define CT 4     // channels staged per LDS round

__global__ __launch_bounds__(256) void conv1d_f32_kernel(
    const float* __restrict__ x,
    const float* __restrict__ W,
    const float* __restrict__ bias,
    float* __restrict__ out)
{
    const int tid = threadIdx.x;
    const int t0  = blockIdx.x * TT;
    const int h0  = blockIdx.y * HT;
    const int b   = blockIdx.z;

    // +Kk pad keeps rows aligned; reads xs[cc][tid+k] are stride-1 -> conflict-free
    __shared__ float xs[CT][TT + Kk];

    float acc[HT];
#pragma unroll
    for (int h = 0; h < HT; ++h) acc[h] = 0.f;

    const float* xb = x + (size_t)b * Cc * Tt;

    for (int c0 = 0; c0 < Cc; c0 += CT) {
        __syncthreads();
        // stage CT channels of x[t0-3 .. t0+TT-1] (259 elements each)
#pragma unroll
        for (int cc = 0; cc < CT; ++cc) {
            for (int j = tid; j < TT + Kk - 1; j += 256) {
                int idx = t0 - (Kk - 1) + j;
                xs[cc][j] = (idx >= 0) ? xb[(size_t)(c0 + cc) * Tt + idx] : 0.f;
            }
        }
        __syncthreads();

#pragma unroll
        for (int cc = 0; cc < CT; ++cc) {
            float xv[Kk];
#pragma unroll
            for (int k = 0; k < Kk; ++k) xv[k] = xs[cc][tid + k];
#pragma unroll
            for (int h = 0; h < HT; ++h) {
                // W pointer is wave-uniform -> scalar loads
                const float* wp = W + (size_t)(h0 + h) * (Cc * Kk) + (size_t)(c0 + cc) * Kk;
#pragma unroll
                for (int k = 0; k < Kk; ++k)
                    acc[h] += wp[k] * xv[k];
            }
        }
    }

#pragma unroll
    for (int h = 0; h < HT; ++h) {
        out[((size_t)b * Hh + (h0 + h)) * Tt + t0 + tid] = acc[h] + bias[h0 + h];
    }
}

extern "C" void kernel_launch(void* const* d_in, const int* in_sizes, int n_in,
                              void* d_out, int out_size, void* d_ws, size_t ws_size,
                              hipStream_t stream) {
    const float* x    = (const float*)d_in[0];
    const float* W    = (const float*)d_in[1];
    const float* bias = (const float*)d_in[2];
    float* out        = (float*)d_out;

    dim3 grid(Tt / TT, Hh / HT, Bb);   // (16, 64, 8)
    dim3 block(256);
    conv1d_f32_kernel<<<grid, block, 0, stream>>>(x, W, bias, out);
}

// Round 2
// 59.081 us; speedup vs baseline: 17.2255x; 17.2255x over previous
//
#include <hip/hip_runtime.h>
#include <hip/hip_bf16.h>

// Causal conv1d as bf16-MFMA batched GEMM.
// out[b,h,t] = sum_{c,k} x[b,c,t+k-3] * W[h, c*4+k] + bias[h]
// B=8, C=256, T=4096, H=512, K=4

#define Bb 8
#define Cc 256
#define Tt 4096
#define Hh 512
#define Kk 4

typedef __attribute__((ext_vector_type(8))) short bf16x8;
typedef __attribute__((ext_vector_type(4))) float f32x4;

// ---------------- workspace layout ----------------
// xT : bf16 [B][T][C]            = 16,777,216 B  at 0
// Wt : bf16 [K][H][C]            =  1,048,576 B  at 16,777,216
// zeros: 64 B                                  at 17,825,792
#define WS_XT_OFF   0
#define WS_WT_OFF   16777216
#define WS_ZERO_OFF 17825792
#define WS_NEEDED   17825856ULL

__device__ __forceinline__ void gload16(const void* g, void* l) {
    __builtin_amdgcn_global_load_lds(
        (const __attribute__((address_space(1))) void*)g,
        (__attribute__((address_space(3))) void*)l, 16, 0, 0);
}

// ---------- prep 1: W[h, c*4+k] f32 -> Wt[k][h][c] bf16, + zero page ----------
__global__ __launch_bounds__(256) void wt_prep_kernel(const float* __restrict__ W,
                                                      __hip_bfloat16* __restrict__ Wt,
                                                      float* __restrict__ zeros) {
    int n = blockIdx.x * 256 + threadIdx.x;           // [0, 4*512*256)
    int c = n & 255;
    int h = (n >> 8) & 511;
    int k = n >> 17;
    Wt[n] = __float2bfloat16(W[h * (Cc * Kk) + c * Kk + k]);
    if (blockIdx.x == 0 && threadIdx.x < 16) zeros[threadIdx.x] = 0.f;
}

// ---------- prep 2: x[b][c][t] f32 -> xT[b][t][c] bf16 (LDS tile transpose) ----------
__global__ __launch_bounds__(256) void xt_prep_kernel(const float* __restrict__ x,
                                                      __hip_bfloat16* __restrict__ xT) {
    __shared__ __hip_bfloat16 tile[64][66];           // +2 pad: conflict-free column reads
    const int t0 = blockIdx.x * 64, c0 = blockIdx.y * 64, b = blockIdx.z;
    const int lt = threadIdx.x & 63, lw = threadIdx.x >> 6;
#pragma unroll
    for (int i = 0; i < 16; ++i) {
        int cc = lw + i * 4;
        tile[cc][lt] = __float2bfloat16(x[((size_t)(b * Cc + c0 + cc)) * Tt + t0 + lt]);
    }
    __syncthreads();
#pragma unroll
    for (int i = 0; i < 16; ++i) {
        int tt = lw + i * 4;
        xT[((size_t)(b * Tt + t0 + tt)) * Cc + c0 + lt] = tile[lt][tt];
    }
}

// ---------- main: 128h x 128t tile, 4 waves, BK=32 channels x 4 conv-k ----------
// LDS: As[k][128][32] bf16 (32768 B) | Bs[144][32] bf16 (9216 B)
#define LDS_A_OFF 0
#define LDS_B_OFF 32768
#define LDS_TOTAL 41984

__global__ __launch_bounds__(256) void conv_mfma_kernel(const __hip_bfloat16* __restrict__ xT,
                                                        const __hip_bfloat16* __restrict__ Wt,
                                                        const float* __restrict__ bias,
                                                        const float* __restrict__ zeros,
                                                        float* __restrict__ out) {
    __shared__ __align__(1024) char smem[LDS_TOTAL];
    const int tid  = threadIdx.x;
    const int lane = tid & 63;
    const int wave = tid >> 6;
    const int wr = wave >> 1, wc = wave & 1;          // 2x2 wave grid (h, t)
    const int l15 = lane & 15, lg = lane >> 4;
    const int t0 = blockIdx.x * 128, h0 = blockIdx.y * 128, b = blockIdx.z;

    f32x4 acc[4][4] = {};

    for (int step = 0; step < 8; ++step) {
        const int c0 = step * 32;
        if (step) __syncthreads();

        // --- stage A: Wt[k][h0..h0+127][c0..c0+31] -> As[k][row][c], 8 x 1KB/wave ---
#pragma unroll
        for (int inst = 0; inst < 8; ++inst) {
            int s = tid + inst * 256;                 // 16B slot id, 2048 total
            int k = s >> 9, rem = s & 511;
            int row = rem >> 2, q = rem & 3;
            const char* src = (const char*)Wt +
                (((size_t)(k * Hh + h0 + row)) * Cc + c0 + q * 8) * 2;
            char* dst = smem + LDS_A_OFF + (wave * 64 + inst * 256) * 16;
            gload16(src, dst);
        }
        // --- stage B: xT[t0-3 .. t0+127][c0..c0+31] -> Bs[row][c] (rows 0..130) ---
#pragma unroll
        for (int inst = 0; inst < 2; ++inst) {
            int s = tid + inst * 256;                 // rows 0..127
            int row = s >> 2, q = s & 3;
            int tg = t0 - 3 + row;
            const void* src = (tg >= 0)
                ? (const void*)((const char*)xT + (((size_t)b * Tt + tg) * Cc + c0 + q * 8) * 2)
                : (const void*)zeros;
            char* dst = smem + LDS_B_OFF + (wave * 64 + inst * 256) * 16;
            gload16(src, dst);
        }
        if (wave == 0) {                              // rows 128..143 (131+ -> zeros)
            int s = tid + 512;
            int row = s >> 2, q = s & 3;
            int tg = t0 - 3 + row;
            const void* src = (row < 131)
                ? (const void*)((const char*)xT + (((size_t)b * Tt + tg) * Cc + c0 + q * 8) * 2)
                : (const void*)zeros;
            char* dst = smem + LDS_B_OFF + 512 * 16;
            gload16(src, dst);
        }
        __syncthreads();

        // --- compute: 4 conv-k passes, 16 mfma each ---
#pragma unroll
        for (int k = 0; k < 4; ++k) {
            bf16x8 af[4], bfr[4];
#pragma unroll
            for (int i = 0; i < 4; ++i) {
                int row = wr * 64 + i * 16 + l15;     // h_local
                af[i] = *(const bf16x8*)(smem + LDS_A_OFF + k * 8192 + row * 64 + lg * 16);
            }
#pragma unroll
            for (int j = 0; j < 4; ++j) {
                int row = wc * 64 + j * 16 + l15 + k; // t_local + k  (conv shift)
                bfr[j] = *(const bf16x8*)(smem + LDS_B_OFF + row * 64 + lg * 16);
            }
#pragma unroll
            for (int i = 0; i < 4; ++i)
#pragma unroll
                for (int j = 0; j < 4; ++j)
                    acc[i][j] = __builtin_amdgcn_mfma_f32_16x16x32_bf16(af[i], bfr[j], acc[i][j], 0, 0, 0);
        }
    }

    // --- epilogue: D row=(lg*4+q) -> h, col=l15 -> t ---
#pragma unroll
    for (int i = 0; i < 4; ++i) {
        int hb = h0 + wr * 64 + i * 16 + lg * 4;
        float4 bs = *(const float4*)&bias[hb];
        const float* bsp = (const float*)&bs;
#pragma unroll
        for (int q = 0; q < 4; ++q) {
            int h = hb + q;
#pragma unroll
            for (int j = 0; j < 4; ++j) {
                int t = t0 + wc * 64 + j * 16 + l15;
                out[((size_t)(b * Hh + h)) * Tt + t] = acc[i][j][q] + bsp[q];
            }
        }
    }
}

// ---------------- fallback (ws too small): round-1 fp32 kernel ----------------
#define TT 256
#define HT 8
#define CT 4
__global__ __launch_bounds__(256) void conv1d_f32_kernel(
    const float* __restrict__ x, const float* __restrict__ W,
    const float* __restrict__ bias, float* __restrict__ out)
{
    const int tid = threadIdx.x;
    const int t0 = blockIdx.x * TT;
    const int h0 = blockIdx.y * HT;
    const int b  = blockIdx.z;
    __shared__ float xs[CT][TT + Kk];
    float acc[HT];
#pragma unroll
    for (int h = 0; h < HT; ++h) acc[h] = 0.f;
    const float* xb = x + (size_t)b * Cc * Tt;
    for (int c0 = 0; c0 < Cc; c0 += CT) {
        __syncthreads();
#pragma unroll
        for (int cc = 0; cc < CT; ++cc)
            for (int j = tid; j < TT + Kk - 1; j += 256) {
                int idx = t0 - (Kk - 1) + j;
                xs[cc][j] = (idx >= 0) ? xb[(size_t)(c0 + cc) * Tt + idx] : 0.f;
            }
        __syncthreads();
#pragma unroll
        for (int cc = 0; cc < CT; ++cc) {
            float xv[Kk];
#pragma unroll
            for (int k = 0; k < Kk; ++k) xv[k] = xs[cc][tid + k];
#pragma unroll
            for (int h = 0; h < HT; ++h) {
                const float* wp = W + (size_t)(h0 + h) * (Cc * Kk) + (size_t)(c0 + cc) * Kk;
#pragma unroll
                for (int k = 0; k < Kk; ++k) acc[h] += wp[k] * xv[k];
            }
        }
    }
#pragma unroll
    for (int h = 0; h < HT; ++h)
        out[((size_t)b * Hh + (h0 + h)) * Tt + t0 + tid] = acc[h] + bias[h0 + h];
}

extern "C" void kernel_launch(void* const* d_in, const int* in_sizes, int n_in,
                              void* d_out, int out_size, void* d_ws, size_t ws_size,
                              hipStream_t stream) {
    const float* x    = (const float*)d_in[0];
    const float* W    = (const float*)d_in[1];
    const float* bias = (const float*)d_in[2];
    float* out        = (float*)d_out;

    if (ws_size >= WS_NEEDED) {
        __hip_bfloat16* xT = (__hip_bfloat16*)((char*)d_ws + WS_XT_OFF);
        __hip_bfloat16* Wt = (__hip_bfloat16*)((char*)d_ws + WS_WT_OFF);
        float* zeros       = (float*)((char*)d_ws + WS_ZERO_OFF);

        wt_prep_kernel<<<dim3((Kk * Hh * Cc) / 256), dim3(256), 0, stream>>>(W, Wt, zeros);
        xt_prep_kernel<<<dim3(Tt / 64, Cc / 64, Bb), dim3(256), 0, stream>>>(x, xT);
        conv_mfma_kernel<<<dim3(Tt / 128, Hh / 128, Bb), dim3(256), 0, stream>>>(xT, Wt, bias, zeros, out);
    } else {
        conv1d_f32_kernel<<<dim3(Tt / TT, Hh / HT, Bb), dim3(256), 0, stream>>>(x, W, bias, out);
    }
}